// Round 4
// baseline (209.501 us; speedup 1.0000x reference)
//
#include <hip/hip_runtime.h>
#include <math.h>

constexpr int Bn   = 32;
constexpr int L    = 65536;            // T*K
constexpr int NCH  = 6;
constexpr int SPAN = 256;              // hexads per wave (64 lanes x 4)
constexpr int NS   = L / SPAN;         // 256 spans per batch row
constexpr int ROW  = L * NCH;
constexpr int EPW_ROW = (L - 1) * NCH;
constexpr int NWAVE = Bn * NS;         // 8192 waves
constexpr float AF = 0.99999f;         // a = 1 - theta*dt
constexpr float DS_ACC  = 0.2f   * 0.004472135954999579f;
constexpr float DS_GYRO = 0.015f * 0.004472135954999579f;

// base^e for e in [0,64), double, square-and-multiply
__device__ __forceinline__ double dpow_lane(double base, int e) {
    double r = 1.0, t = base;
    #pragma unroll
    for (int k = 0; k < 6; ++k) { if (e & (1 << k)) r *= t; t *= t; }
    return r;
}

// load 4 consecutive hexads of scaled innovation starting at element gl0
// xv[j*6+c]; handles the gl0==0 eps0 seed (no OOB epw read)
__device__ __forceinline__ void load_x24(const float* __restrict__ epw,
                                         const float* __restrict__ eps0,
                                         int b, int gl0, float xv[24]) {
    const float sc[6] = {DS_ACC, DS_ACC, DS_ACC, DS_GYRO, DS_GYRO, DS_GYRO};
    if (gl0 == 0) {
        const float* e0 = eps0 + b * NCH;
        xv[0] = e0[0] * 0.2f;   xv[1] = e0[1] * 0.2f;   xv[2] = e0[2] * 0.2f;
        xv[3] = e0[3] * 0.015f; xv[4] = e0[4] * 0.015f; xv[5] = e0[5] * 0.015f;
        const float* p = epw + (size_t)b * EPW_ROW;
        #pragma unroll
        for (int f = 6; f < 24; ++f) xv[f] = p[f - 6] * sc[f % 6];
    } else {
        const float2* p = (const float2*)(epw + (size_t)b * EPW_ROW + (size_t)(gl0 - 1) * NCH);
        #pragma unroll
        for (int q = 0; q < 12; ++q) {
            float2 t = p[q];
            xv[2 * q]     = t.x * sc[(2 * q) % 6];
            xv[2 * q + 1] = t.y * sc[(2 * q + 1) % 6];
        }
    }
}

// ---------- K1: per-span weighted aggregate, transposed output ----------
__global__ __launch_bounds__(256) void k_partials(
    const float* __restrict__ eps0,
    const float* __restrict__ epw,
    float* __restrict__ part)   // [chain][NS]
{
    int lane = threadIdx.x & 63;
    int w = blockIdx.x * 4 + (threadIdx.x >> 6);
    int b = w / NS, s = w % NS;
    int gl0 = s * SPAN + lane * 4;

    double ad = (double)AF;
    double A4d = ad * ad; A4d *= A4d;                 // a^4
    float wrev = (float)dpow_lane(A4d, 63 - lane);    // (a^4)^(63-lane)

    float xv[24];
    load_x24(epw, eps0, b, gl0, xv);

    float z0, z1, z2, z3, z4, z5;
    float* zp[6] = {&z0, &z1, &z2, &z3, &z4, &z5};
    #pragma unroll
    for (int c = 0; c < 6; ++c) {
        float t = xv[c];
        #pragma unroll
        for (int j = 1; j < 4; ++j) t = fmaf(AF, t, xv[j * 6 + c]);
        float z = wrev * t;
        #pragma unroll
        for (int m = 1; m < 64; m <<= 1) z += __shfl_xor(z, m, 64);
        *zp[c] = z;
    }
    if (lane < 6) {
        float v = z0;
        if (lane == 1) v = z1; else if (lane == 2) v = z2;
        else if (lane == 3) v = z3; else if (lane == 4) v = z4;
        else if (lane == 5) v = z5;
        part[((size_t)b * NCH + lane) * NS + s] = v;
    }
}

// ---------- K2: per-chain scan of span aggregates (coalesced float4) ----------
__global__ __launch_bounds__(64) void k_scan(
    const float* __restrict__ part,    // [chain][NS]
    float* __restrict__ carry)         // [w][ch]
{
    int lane = threadIdx.x;
    int chain = blockIdx.x;            // b*6 + c
    int b = chain / NCH, c = chain % NCH;

    double a = (double)AF;
    double A = a;
    #pragma unroll
    for (int k = 0; k < 8; ++k) A *= A;   // a^256 = a^SPAN
    double A4 = A * A; A4 *= A4;          // a^1024 (per-lane: 4 spans)

    const float4* pp = (const float4*)(part + (size_t)chain * NS);
    float4 pv = pp[lane];

    double t = (double)pv.x;
    t = A * t + (double)pv.y; t = A * t + (double)pv.z; t = A * t + (double)pv.w;

    double I = t, m = A4;
    #pragma unroll
    for (int d = 1; d <= 32; d <<= 1) {
        double up = __shfl_up(I, d, 64);
        if (lane >= d) I = m * up + I;
        m = m * m;
    }
    double cin = __shfl_up(I, 1, 64);
    if (lane == 0) cin = 0.0;

    float pvv[4] = {pv.x, pv.y, pv.z, pv.w};
    double e = cin;
    #pragma unroll
    for (int k = 0; k < 4; ++k) {
        int s = lane * 4 + k;
        carry[((size_t)b * NS + s) * NCH + c] = (float)e;  // E_{s-1}
        e = A * e + (double)pvv[k];
    }
}

// ---------- K3: fused hierarchical scan + elementwise, float4 I/O ----------
__global__ __launch_bounds__(256) void k_apply(
    const float* __restrict__ imu,
    const float* __restrict__ eps0,
    const float* __restrict__ epw,
    const float* __restrict__ mn,
    const float* __restrict__ carry,
    float* __restrict__ out)
{
    int lane = threadIdx.x & 63;
    int w = blockIdx.x * 4 + (threadIdx.x >> 6);
    int b = w / NS, s = w % NS;
    int gl0 = s * SPAN + lane * 4;

    double ad = (double)AF;
    double A4d = ad * ad; A4d *= A4d;                 // a^4
    const float A4 = (float)A4d;
    const float A4lane = (float)dpow_lane(A4d, lane); // (a^4)^lane
    const float apj[4] = {AF, (float)(ad * ad), (float)(ad * ad * ad), A4};

    float xv[24];
    load_x24(epw, eps0, b, gl0, xv);

    // in-lane serial scan per channel: xv[j*6+c] -> s_j[c]
    #pragma unroll
    for (int j = 1; j < 4; ++j)
        #pragma unroll
        for (int c = 0; c < 6; ++c)
            xv[j * 6 + c] = fmaf(AF, xv[(j - 1) * 6 + c], xv[j * 6 + c]);

    // Kogge-Stone over lane totals, then fold span carry
    float F[6];
    #pragma unroll
    for (int c = 0; c < 6; ++c) {
        float I = xv[18 + c], m = A4;
        #pragma unroll
        for (int d = 1; d < 64; d <<= 1) {
            float up = __shfl_up(I, d, 64);
            if (lane >= d) I = fmaf(m, up, I);
            m *= m;
        }
        float E = __shfl_up(I, 1, 64);
        if (lane == 0) E = 0.f;
        F[c] = fmaf(A4lane, carry[(size_t)w * NCH + c], E);
    }
    // bias_j[c] = s_j[c] + a^(j+1) * F[c]
    #pragma unroll
    for (int j = 0; j < 4; ++j)
        #pragma unroll
        for (int c = 0; c < 6; ++c)
            xv[j * 6 + c] = fmaf(apj[j], F[c], xv[j * 6 + c]);

    const float inv = 1.0f / 65535.0f, twopi = 6.283185307179586f;
    float tmp[4];
    #pragma unroll
    for (int j = 0; j < 4; ++j) {
        float tt = (float)(gl0 + j) * inv;
        tmp[j] = fmaf(5.0f, __sinf(twopi * tt), fmaf(2.0f, tt, 20.0f));
    }
    const float ns[6] = {0.1f, 0.1f, 0.1f, 0.01f, 0.01f, 0.01f};
    const float tc[6] = {0.001f, 0.001f, 0.001f, 0.01f, 0.01f, 0.01f};

    size_t roff = (size_t)b * ROW + (size_t)gl0 * NCH;
    const float4* ip = (const float4*)(imu + roff);
    const float4* mp = (const float4*)(mn + roff);
    float4* op = (float4*)(out + roff);
    #pragma unroll
    for (int q = 0; q < 6; ++q) {
        float4 iv = ip[q], mv = mp[q], ov;
        float* ivf = (float*)&iv; float* mvf = (float*)&mv; float* ovf = (float*)&ov;
        #pragma unroll
        for (int r = 0; r < 4; ++r) {
            int f = q * 4 + r, j = f / 6, c = f % 6;
            ovf[r] = ivf[r] + xv[f] + mvf[r] * ns[c] + tmp[j] * tc[c];
        }
        op[q] = ov;
    }
}

extern "C" void kernel_launch(void* const* d_in, const int* in_sizes, int n_in,
                              void* d_out, int out_size, void* d_ws, size_t ws_size,
                              hipStream_t stream) {
    const float* imu  = (const float*)d_in[0];   // [B, L, 6]
    const float* eps0 = (const float*)d_in[1];   // [B, 6]
    const float* epw  = (const float*)d_in[2];   // [B, L-1, 6]
    const float* mn   = (const float*)d_in[3];   // [B, L, 6]
    float* out = (float*)d_out;

    float* part  = (float*)d_ws;                     // Bn*6*NS floats
    float* carry = part + (size_t)Bn * NCH * NS;     // NWAVE*6 floats

    k_partials<<<NWAVE / 4, 256, 0, stream>>>(eps0, epw, part);
    k_scan<<<Bn * NCH, 64, 0, stream>>>(part, carry);
    k_apply<<<NWAVE / 4, 256, 0, stream>>>(imu, eps0, epw, mn, carry, out);
}